// Round 4
// baseline (580.604 us; speedup 1.0000x reference)
//
#include <hip/hip_runtime.h>

#define HSZ 32
#define TT  1024
#define LOG2E 1.44269504088896340736f

typedef float v2f __attribute__((ext_vector_type(2)));
typedef float v4f __attribute__((ext_vector_type(4)));

__device__ __forceinline__ float frcp(float x)  { return __builtin_amdgcn_rcpf(x); }
__device__ __forceinline__ float fexp2(float x) { return __builtin_amdgcn_exp2f(x); }

// One wave (64 lanes) per batch element; 4096 blocks of 64 threads -> 4 waves/SIMD.
// Lane j (j = lane&31) owns hidden unit j. Lanes 0-31 hold gate rows (i, f);
// lanes 32-63 hold gate rows (g, o). Weights pre-scaled by -log2e (sigmoid rows)
// or -2log2e (tanh row) so every activation is rcp(1+exp2(z)) with no extra mul;
// per-lane (A1,B1) constants make tanh-vs-sigmoid branch-free. tanh(g), sigm(o)
// cross from the upper half via shfl_xor(32); lower half owns c and h. Upper
// half computes harmless garbage c/h; its h-store goes to a trash LDS row.
// Weight regs are pinned INSIDE the t-loop so LLVM cannot rematerialize the
// global loads per step (the round-3 failure: VGPR=96 < weight footprint).
__global__ __launch_bounds__(64, 4)
void lstm_fused_kernel(const float* __restrict__ x,
                       const float* __restrict__ W_ih,
                       const float* __restrict__ W_hh,
                       const float* __restrict__ b_ih,
                       const float* __restrict__ b_hh,
                       const float* __restrict__ W1, const float* __restrict__ b1,
                       const float* __restrict__ W2, const float* __restrict__ b2,
                       const float* __restrict__ W3, const float* __restrict__ b3,
                       float* __restrict__ out)
{
  __shared__ __align__(16) float hlds[2][HSZ];   // row 0 real, row 1 trash

  const int lane = threadIdx.x;          // 0..63 (one wave per block)
  const int half = lane >> 5;            // 0: gates i,f ; 1: gates g,o
  const int j    = lane & 31;            // hidden unit owned by this lane
  const int elem = blockIdx.x;           // batch element

  const int r1 = (half ? 2 : 0) * HSZ + j;   // gate-slot-1 row: i or g
  const int r2 = (half ? 3 : 1) * HSZ + j;   // gate-slot-2 row: f or o
  const float s1 = half ? (-2.0f * LOG2E) : (-LOG2E);
  const float s2 = -LOG2E;
  const float A1 = half ? 2.0f : 1.0f;       // act1 = A1*rcp(1+exp2(z1)) + B1
  const float B1 = half ? -1.0f : 0.0f;      // -> sigm (lower) or tanh (upper)

  // ---- per-lane pre-scaled weight rows (64 VGPRs total) ----
  v2f w1[16], w2[16];
  {
    const v4f* p1 = reinterpret_cast<const v4f*>(W_hh + r1 * HSZ);
    const v4f* p2 = reinterpret_cast<const v4f*>(W_hh + r2 * HSZ);
#pragma unroll
    for (int k4 = 0; k4 < 8; ++k4) {
      v4f a = p1[k4] * s1;
      v4f b = p2[k4] * s2;
      w1[2*k4] = a.lo; w1[2*k4+1] = a.hi;
      w2[2*k4] = b.lo; w2[2*k4+1] = b.hi;
    }
  }
  const float bz1  = s1 * (b_ih[r1] + b_hh[r1]);
  const float bz2  = s2 * (b_ih[r2] + b_hh[r2]);
  const float wxz1 = s1 * W_ih[r1];          // I == 1
  const float wxz2 = s2 * W_ih[r2];

  v2f h2[16];
#pragma unroll
  for (int k = 0; k < 16; ++k) h2[k] = (v2f){0.0f, 0.0f};
  float c = 0.0f;

  const float* xrow = x + (size_t)elem * TT;

#pragma unroll 1
  for (int t0 = 0; t0 < TT; t0 += 64) {
    float xc = xrow[t0 + lane];              // coalesced: 64 timesteps per load

    // pin weights: opaque redefine each chunk -> loads cannot be remat'd into
    // the step loop; values must stay register-resident
#pragma unroll
    for (int k = 0; k < 16; k += 4) {
      asm volatile("" : "+v"(w1[k]), "+v"(w1[k+1]), "+v"(w1[k+2]), "+v"(w1[k+3]),
                        "+v"(w2[k]), "+v"(w2[k+1]), "+v"(w2[k+2]), "+v"(w2[k+3]));
    }

#pragma unroll 1
    for (int s = 0; s < 64; ++s) {
      float xt = __shfl(xc, s);              // broadcast x_t across the wave

      v2f a1 = (v2f){bz1, 0.0f};
      v2f a2 = (v2f){bz2, 0.0f};
#pragma unroll
      for (int k = 0; k < 16; ++k) {
        a1 = __builtin_elementwise_fma(w1[k], h2[k], a1);
        a2 = __builtin_elementwise_fma(w2[k], h2[k], a2);
      }
      float z1 = a1.x + fmaf(xt, wxz1, a1.y);
      float z2 = a2.x + fmaf(xt, wxz2, a2.y);

      float act1 = fmaf(A1, frcp(1.0f + fexp2(z1)), B1); // sigm(i) | tanh(g)
      float act2 = frcp(1.0f + fexp2(z2));               // sigm(f) | sigm(o)

      float tg = __shfl_xor(act1, 32);       // lower receives tanh(g)
      float so = __shfl_xor(act2, 32);       // lower receives sigm(o)

      c = fmaf(act2, c, act1 * tg);          // lower: sigm(f)*c + sigm(i)*tanh(g)
      float tc = fmaf(2.0f, frcp(1.0f + fexp2(c * (-2.0f * LOG2E))), -1.0f);
      float h = so * tc;                     // lower: sigm(o)*tanh(c)

      hlds[half][j] = h;                     // upper half -> trash row 1
#pragma unroll
      for (int k4 = 0; k4 < 8; ++k4) {       // all lanes reload full h (bcast)
        v4f v = *reinterpret_cast<const v4f*>(&hlds[0][4 * k4]);
        h2[2*k4]   = v.lo;
        h2[2*k4+1] = v.hi;
      }
    }
  }

  // ---- MLP head 32->16->8->1 on final h (LDS row 0), redundant per lane ----
  const float* hrow = &hlds[0][0];
  float a1v[16];
#pragma unroll
  for (int r = 0; r < 16; ++r) {
    float acc = b1[r];
#pragma unroll
    for (int k = 0; k < 32; ++k) acc = fmaf(W1[r * 32 + k], hrow[k], acc);
    a1v[r] = fmaxf(acc, 0.0f);
  }
  float a2v[8];
#pragma unroll
  for (int r = 0; r < 8; ++r) {
    float acc = b2[r];
#pragma unroll
    for (int k = 0; k < 16; ++k) acc = fmaf(W2[r * 16 + k], a1v[k], acc);
    a2v[r] = fmaxf(acc, 0.0f);
  }
  float o = b3[0];
#pragma unroll
  for (int k = 0; k < 8; ++k) o = fmaf(W3[k], a2v[k], o);

  if (lane == 0) out[elem] = o;
}

extern "C" void kernel_launch(void* const* d_in, const int* in_sizes, int n_in,
                              void* d_out, int out_size, void* d_ws, size_t ws_size,
                              hipStream_t stream) {
  const float* x    = (const float*)d_in[0];
  const float* W_ih = (const float*)d_in[1];
  const float* W_hh = (const float*)d_in[2];
  const float* b_ih = (const float*)d_in[3];
  const float* b_hh = (const float*)d_in[4];
  const float* W1   = (const float*)d_in[5];
  const float* b1   = (const float*)d_in[6];
  const float* W2   = (const float*)d_in[7];
  const float* b2   = (const float*)d_in[8];
  const float* W3   = (const float*)d_in[9];
  const float* b3   = (const float*)d_in[10];
  float* out = (float*)d_out;

  const int B = in_sizes[0] / TT;            // 4096
  dim3 grid(B), block(64);                   // one wave per element
  hipLaunchKernelGGL(lstm_fused_kernel, grid, block, 0, stream,
                     x, W_ih, W_hh, b_ih, b_hh, W1, b1, W2, b2, W3, b3, out);
}